// Round 8
// baseline (8466.220 us; speedup 1.0000x reference)
//
#include <hip/hip_runtime.h>
#include <hip/hip_bf16.h>

#define V  32000
#define D  512
#define H  512
#define B  32
#define T  128
#define L  48
#define KLIN 1024
#define KGRU 1536
#define RESCUE_DELTA 0.04f
#define MAXCAND 16

typedef __attribute__((ext_vector_type(8))) short bf16x8;
typedef __attribute__((ext_vector_type(4))) float f32x4;

#define MFMA16(a, b, c) __builtin_amdgcn_mfma_f32_16x16x32_bf16(a, b, c, 0, 0, 0)

// ---------- f32 -> (bf16 hi, bf16 lo) split, RNE ----------
__device__ __forceinline__ void split1(float f, unsigned short* hi, unsigned short* lo) {
    unsigned u  = __float_as_uint(f);
    unsigned uh = u + (0x7FFFu + ((u >> 16) & 1u));
    unsigned short hs = (unsigned short)(uh >> 16);
    float hf = __uint_as_float(((unsigned)hs) << 16);
    float l  = f - hf;
    unsigned ul = __float_as_uint(l);
    ul += 0x7FFFu + ((ul >> 16) & 1u);
    *hi = hs;
    *lo = (unsigned short)(ul >> 16);
}

__device__ __forceinline__ void split8(const float* __restrict__ p, bf16x8& hi, bf16x8& lo) {
    float4 w0 = reinterpret_cast<const float4*>(p)[0];
    float4 w1 = reinterpret_cast<const float4*>(p)[1];
    float w[8] = {w0.x, w0.y, w0.z, w0.w, w1.x, w1.y, w1.z, w1.w};
    #pragma unroll
    for (int i = 0; i < 8; ++i) {
        unsigned u  = __float_as_uint(w[i]);
        unsigned uh = u + (0x7FFFu + ((u >> 16) & 1u));
        unsigned short hs = (unsigned short)(uh >> 16);
        float hf = __uint_as_float(((unsigned)hs) << 16);
        float l  = w[i] - hf;
        unsigned ul = __float_as_uint(l);
        ul += 0x7FFFu + ((ul >> 16) & 1u);
        hi[i] = (short)hs;
        lo[i] = (short)(ul >> 16);
    }
}

// top-2 merge
__device__ __forceinline__ void merge2(float& m1, int& i1, float& m2, int& i2,
                                       float om1, int oi1, float om2, int oi2) {
    bool ogt = (om1 > m1) || (om1 == m1 && oi1 < i1);
    float t1 = ogt ? om1 : m1; int ti1 = ogt ? oi1 : i1;
    float l1 = ogt ? m1 : om1; int li1 = ogt ? i1 : oi1;
    float w2 = ogt ? om2 : m2; int wi2 = ogt ? oi2 : i2;
    bool lgt = (l1 > w2) || (l1 == w2 && li1 < wi2);
    m1 = t1; i1 = ti1;
    m2 = lgt ? l1 : w2; i2 = lgt ? li1 : wi2;
}

// ---------- one-time: linW -> bf16 hi only (linear [col][k] layout, as R5) ----------
__global__ void presplit_lin_hi(const float* __restrict__ src, unsigned short* __restrict__ hi)
{
    long i = (long)blockIdx.x * 256 + threadIdx.x;
    if (i >= (long)V * 128) return;
    bf16x8 h8, l8;
    split8(src + i * 8, h8, l8);
    *(bf16x8*)(hi + i * 8) = h8;
}

// ---------- one-time: split gru weights into combined [1536][1536] K-layout ----------
__global__ void presplit_gru(const float* __restrict__ Wih, const float* __restrict__ Whh,
                             unsigned short* __restrict__ hi, unsigned short* __restrict__ lo)
{
    int i = blockIdx.x * 256 + threadIdx.x;
    if (i >= 1536 * 192) return;
    int col = i / 192, k = (i % 192) * 8;
    const float* src = (k < 1024) ? (Wih + (size_t)col * 1024 + k)
                                  : (Whh + (size_t)col * 512 + (k - 1024));
    bf16x8 h8, l8;
    split8(src, h8, l8);
    *(bf16x8*)(hi + (size_t)col * KGRU + k) = h8;
    *(bf16x8*)(lo + (size_t)col * KGRU + k) = l8;
}

// ---------- init: ctx0 into Xg/Xl/Xf; Xg h-part = 0; h_t = 0 ----------
__global__ void init_state(const float* __restrict__ context, float* __restrict__ h_t,
                           unsigned short* __restrict__ Xghi, unsigned short* __restrict__ Xglo,
                           unsigned short* __restrict__ Xlhi, unsigned short* __restrict__ Xllo,
                           float* __restrict__ Xf)
{
    int idx = blockIdx.x * 256 + threadIdx.x;   // 0..B*H-1
    int b = idx >> 9, j = idx & 511;
    float c = context[b * H + j];
    split1(c, &Xghi[b * KGRU + 512 + j], &Xglo[b * KGRU + 512 + j]);
    split1(c, &Xlhi[b * KLIN + 512 + j], &Xllo[b * KLIN + 512 + j]);
    Xf[b * KLIN + 512 + j] = c;
    Xghi[b * KGRU + 1024 + j] = 0;
    Xglo[b * KGRU + 1024 + j] = 0;
    h_t[j * 32 + b] = 0.f;
}

// ---------- energies = enc @ attn_W^T + attn_b (once) ----------
__global__ void __launch_bounds__(256) energies_gemm(
    const float* __restrict__ enc, const float* __restrict__ attnW,
    const float* __restrict__ attnb, float* __restrict__ energies)
{
    int wave = threadIdx.x >> 6, lane = threadIdx.x & 63;
    int col = blockIdx.y * 64 + wave * 16 + (lane & 15);
    int kg  = (lane >> 4) * 8;
    int arow0 = blockIdx.x * 32 + (lane & 15);
    f32x4 acc0 = {0.f,0.f,0.f,0.f}, acc1 = {0.f,0.f,0.f,0.f};
    for (int k0 = 0; k0 < 512; k0 += 32) {
        bf16x8 bh, bl;   split8(attnW + (size_t)col * 512 + k0 + kg, bh, bl);
        bf16x8 a0h, a0l; split8(enc + (size_t)arow0 * 512 + k0 + kg, a0h, a0l);
        bf16x8 a1h, a1l; split8(enc + (size_t)(arow0 + 16) * 512 + k0 + kg, a1h, a1l);
        acc0 = MFMA16(a0h, bh, acc0);  acc1 = MFMA16(a1h, bh, acc1);
        acc0 = MFMA16(a0l, bh, acc0);  acc1 = MFMA16(a1l, bh, acc1);
        acc0 = MFMA16(a0h, bl, acc0);  acc1 = MFMA16(a1h, bl, acc1);
    }
    float bias = attnb[col];
    int r0 = (lane >> 4) * 4;
    #pragma unroll
    for (int i = 0; i < 4; ++i) {
        int row = blockIdx.x * 32 + r0 + i;
        energies[(size_t)row * 512 + col]        = acc0[i] + bias;
        energies[(size_t)(row + 16) * 512 + col] = acc1[i] + bias;
    }
}

// ---------- fused: redundant finalize(t-1) + GRU(t). 32 blocks x 384 threads ----------
// Phase A: every block independently reduces the 500 partials for all 32 batches
//          (argmax + exact-f32 rescue); block 0 also writes lse(t-1). No cross-block sync.
// Phase B: R2-proven MFMA GRU; e-third of K read straight from emb[argmax] with
//          in-loop f32->bf16 hi/lo split.
__global__ void __launch_bounds__(384) gru_fin(
    const int* __restrict__ inputs, const float* __restrict__ emb,
    const unsigned short* __restrict__ Ghi, const unsigned short* __restrict__ Glo,
    const float* __restrict__ bih, const float* __restrict__ bhh,
    const float* __restrict__ linW, const float* __restrict__ linb,
    const unsigned short* __restrict__ Xghi_r, const unsigned short* __restrict__ Xglo_r,
    unsigned short* __restrict__ Xghi_n, unsigned short* __restrict__ Xglo_n,
    unsigned short* __restrict__ Xlhi_w, unsigned short* __restrict__ Xllo_w,
    float* __restrict__ Xf_w, const float* __restrict__ Xf_prev,
    float* __restrict__ h_t,
    const float* __restrict__ Pm, const int* __restrict__ Pa,
    const float* __restrict__ Pm2, const int* __restrict__ Pa2,
    const float* __restrict__ Ps,
    float* __restrict__ lse_buf, int t)
{
    __shared__ float AI[3][32][16], AH[3][32][16];
    __shared__ float R[32][16], Z[32][16];
    __shared__ int   sAl[32];
    __shared__ int   clist[6][MAXCAND];
    __shared__ int   ncand[6];
    const int tid = threadIdx.x;
    const int w = tid >> 6, lane = tid & 63;

    // ===== phase A =====
    if (t == 0) {
        if (tid < 32) sAl[tid] = inputs[tid];
    } else {
        // wave wv handles batches b = wv, wv+6, ...
        for (int b = w; b < 32; b += 6) {
            // pass 1: max + argmax over 500 block-partials
            float m = -INFINITY; int a = 0x7fffffff;
            for (int i = lane; i < 500; i += 64) {
                float om = Pm[b * 500 + i]; int oa = Pa[b * 500 + i];
                if (om > m || (om == m && oa < a)) { m = om; a = oa; }
            }
            #pragma unroll
            for (int d = 1; d < 64; d <<= 1) {
                float om = __shfl_xor(m, d); int oa = __shfl_xor(a, d);
                if (om > m || (om == m && oa < a)) { m = om; a = oa; }
            }
            float M = m, thresh = M - RESCUE_DELTA;
            // pass 2: sumexp + candidate collection (top-2 per partial block)
            if (lane == 0) ncand[w] = 0;
            float S = 0.f;
            for (int i = lane; i < 500; i += 64) {
                float pm = Pm[b * 500 + i];
                S += Ps[b * 500 + i] * expf(pm - M);
                if (pm >= thresh) { int p = atomicAdd(&ncand[w], 1); if (p < MAXCAND) clist[w][p] = Pa[b * 500 + i]; }
                if (Pm2[b * 500 + i] >= thresh) { int p = atomicAdd(&ncand[w], 1); if (p < MAXCAND) clist[w][p] = Pa2[b * 500 + i]; }
            }
            #pragma unroll
            for (int d = 1; d < 64; d <<= 1) S += __shfl_xor(S, d);
            if (blockIdx.x == 0 && lane == 0) lse_buf[b * L + (t - 1)] = M + logf(S);
            // exact f32 dots for candidates, full wave per candidate
            int nc = ncand[w]; nc = nc < MAXCAND ? nc : MAXCAND;
            float best = -INFINITY; int bi = 0x7fffffff;
            for (int ci = 0; ci < nc; ++ci) {
                int col = clist[w][ci];
                const float* wr = linW + (size_t)col * 1024 + lane * 16;
                const float* xr = Xf_prev + (size_t)b * KLIN + lane * 16;
                float s = 0.f;
                #pragma unroll
                for (int jj = 0; jj < 16; jj += 4) {
                    float4 av = *(const float4*)(wr + jj);
                    float4 xv = *(const float4*)(xr + jj);
                    s += av.x * xv.x + av.y * xv.y + av.z * xv.z + av.w * xv.w;
                }
                #pragma unroll
                for (int d = 1; d < 64; d <<= 1) s += __shfl_xor(s, d);
                s += linb[col];
                if (s > best || (s == best && col < bi)) { best = s; bi = col; }
            }
            if (lane == 0) sAl[b] = bi;
        }
    }
    __syncthreads();

    // ===== phase B: GRU =====
    {
        int g = (w < 3) ? w : w - 3;
        int c = lane & 15, grp = lane >> 4, kg = grp * 8;
        int j = blockIdx.x * 16 + c;
        int gcol = g * 512 + j;
        const unsigned short* wh = Ghi + (size_t)gcol * KGRU;
        const unsigned short* wl = Glo + (size_t)gcol * KGRU;
        const unsigned short* xh = Xghi_r + (size_t)c * KGRU;
        const unsigned short* xl = Xglo_r + (size_t)c * KGRU;
        f32x4 aI0 = {0.f,0.f,0.f,0.f}, aI1 = {0.f,0.f,0.f,0.f};
        f32x4 aH0 = {0.f,0.f,0.f,0.f}, aH1 = {0.f,0.f,0.f,0.f};
        if (w < 3) {
            // gi over e-part: k0 in [0,512), X = emb rows (on-the-fly hi/lo split)
            const float* e0p = emb + (size_t)sAl[c] * 512;
            const float* e1p = emb + (size_t)sAl[c + 16] * 512;
            for (int k0 = 0; k0 < 512; k0 += 32) {
                bf16x8 bh = *(const bf16x8*)(wh + k0 + kg);
                bf16x8 bl = *(const bf16x8*)(wl + k0 + kg);
                bf16x8 a0h, a0l, a1h, a1l;
                split8(e0p + k0 + kg, a0h, a0l);
                split8(e1p + k0 + kg, a1h, a1l);
                aI0 = MFMA16(a0h, bh, aI0);  aI1 = MFMA16(a1h, bh, aI1);
                aI0 = MFMA16(a0l, bh, aI0);  aI1 = MFMA16(a1l, bh, aI1);
                aI0 = MFMA16(a0h, bl, aI0);  aI1 = MFMA16(a1h, bl, aI1);
            }
            // gh first half: k0 in [1024,1280)
            for (int k0 = 1024; k0 < 1280; k0 += 32) {
                bf16x8 bh = *(const bf16x8*)(wh + k0 + kg);
                bf16x8 bl = *(const bf16x8*)(wl + k0 + kg);
                bf16x8 a0h = *(const bf16x8*)(xh + k0 + kg);
                bf16x8 a0l = *(const bf16x8*)(xl + k0 + kg);
                bf16x8 a1h = *(const bf16x8*)(xh + 16 * KGRU + k0 + kg);
                bf16x8 a1l = *(const bf16x8*)(xl + 16 * KGRU + k0 + kg);
                aH0 = MFMA16(a0h, bh, aH0);  aH1 = MFMA16(a1h, bh, aH1);
                aH0 = MFMA16(a0l, bh, aH0);  aH1 = MFMA16(a1l, bh, aH1);
                aH0 = MFMA16(a0h, bl, aH0);  aH1 = MFMA16(a1h, bl, aH1);
            }
        } else {
            // gi over ctx-part: k0 in [512,1024), X from global bf16 buffers
            for (int k0 = 512; k0 < 1024; k0 += 32) {
                bf16x8 bh = *(const bf16x8*)(wh + k0 + kg);
                bf16x8 bl = *(const bf16x8*)(wl + k0 + kg);
                bf16x8 a0h = *(const bf16x8*)(xh + k0 + kg);
                bf16x8 a0l = *(const bf16x8*)(xl + k0 + kg);
                bf16x8 a1h = *(const bf16x8*)(xh + 16 * KGRU + k0 + kg);
                bf16x8 a1l = *(const bf16x8*)(xl + 16 * KGRU + k0 + kg);
                aI0 = MFMA16(a0h, bh, aI0);  aI1 = MFMA16(a1h, bh, aI1);
                aI0 = MFMA16(a0l, bh, aI0);  aI1 = MFMA16(a1l, bh, aI1);
                aI0 = MFMA16(a0h, bl, aI0);  aI1 = MFMA16(a1h, bl, aI1);
            }
            // gh second half: k0 in [1280,1536)
            for (int k0 = 1280; k0 < 1536; k0 += 32) {
                bf16x8 bh = *(const bf16x8*)(wh + k0 + kg);
                bf16x8 bl = *(const bf16x8*)(wl + k0 + kg);
                bf16x8 a0h = *(const bf16x8*)(xh + k0 + kg);
                bf16x8 a0l = *(const bf16x8*)(xl + k0 + kg);
                bf16x8 a1h = *(const bf16x8*)(xh + 16 * KGRU + k0 + kg);
                bf16x8 a1l = *(const bf16x8*)(xl + 16 * KGRU + k0 + kg);
                aH0 = MFMA16(a0h, bh, aH0);  aH1 = MFMA16(a1h, bh, aH1);
                aH0 = MFMA16(a0l, bh, aH0);  aH1 = MFMA16(a1l, bh, aH1);
                aH0 = MFMA16(a0h, bl, aH0);  aH1 = MFMA16(a1h, bl, aH1);
            }
        }
        if (w >= 3) {
            #pragma unroll
            for (int i = 0; i < 4; ++i) {
                AI[g][grp * 4 + i][c] = aI0[i];  AI[g][grp * 4 + i + 16][c] = aI1[i];
                AH[g][grp * 4 + i][c] = aH0[i];  AH[g][grp * 4 + i + 16][c] = aH1[i];
            }
        }
        __syncthreads();
        float gi[8], gh[8];
        if (w < 3) {
            float bi = bih[gcol], bhv = bhh[gcol];
            #pragma unroll
            for (int i = 0; i < 4; ++i) {
                gi[i]     = aI0[i] + AI[g][grp * 4 + i][c]      + bi;
                gi[i + 4] = aI1[i] + AI[g][grp * 4 + i + 16][c] + bi;
                gh[i]     = aH0[i] + AH[g][grp * 4 + i][c]      + bhv;
                gh[i + 4] = aH1[i] + AH[g][grp * 4 + i + 16][c] + bhv;
            }
            if (w == 0) {
                #pragma unroll
                for (int i = 0; i < 8; ++i) {
                    int b = (i < 4) ? grp * 4 + i : grp * 4 + (i - 4) + 16;
                    R[b][c] = 1.f / (1.f + expf(-(gi[i] + gh[i])));
                }
            } else if (w == 1) {
                #pragma unroll
                for (int i = 0; i < 8; ++i) {
                    int b = (i < 4) ? grp * 4 + i : grp * 4 + (i - 4) + 16;
                    Z[b][c] = 1.f / (1.f + expf(-(gi[i] + gh[i])));
                }
            }
        }
        __syncthreads();
        if (w == 2) {
            int j2 = j;
            float4 h0 = *(const float4*)(h_t + (size_t)j2 * 32 + grp * 4);
            float4 h1 = *(const float4*)(h_t + (size_t)j2 * 32 + grp * 4 + 16);
            float hold[8] = {h0.x, h0.y, h0.z, h0.w, h1.x, h1.y, h1.z, h1.w};
            float hn[8];
            #pragma unroll
            for (int i = 0; i < 8; ++i) {
                int b = (i < 4) ? grp * 4 + i : grp * 4 + (i - 4) + 16;
                float n = tanhf(gi[i] + R[b][c] * gh[i]);
                float z = Z[b][c];
                hn[i] = (1.f - z) * n + z * hold[i];
            }
            *(float4*)(h_t + (size_t)j2 * 32 + grp * 4)      = make_float4(hn[0], hn[1], hn[2], hn[3]);
            *(float4*)(h_t + (size_t)j2 * 32 + grp * 4 + 16) = make_float4(hn[4], hn[5], hn[6], hn[7]);
            #pragma unroll
            for (int i = 0; i < 8; ++i) {
                int b = (i < 4) ? grp * 4 + i : grp * 4 + (i - 4) + 16;
                split1(hn[i], &Xlhi_w[(size_t)b * KLIN + j2], &Xllo_w[(size_t)b * KLIN + j2]);
                Xf_w[(size_t)b * KLIN + j2] = hn[i];
                split1(hn[i], &Xghi_n[(size_t)b * KGRU + 1024 + j2], &Xglo_n[(size_t)b * KGRU + 1024 + j2]);
            }
        }
    }
}

// ---------- score (2-pass, Whi only; blocks 0..499) + attention/ctx (500..531) ----------
__global__ void __launch_bounds__(256) score_attn(
    const unsigned short* __restrict__ Whi, const float* __restrict__ linb,
    const unsigned short* __restrict__ Xlhi_r, const unsigned short* __restrict__ Xllo_r,
    unsigned short* __restrict__ Xlhi_n, unsigned short* __restrict__ Xllo_n,
    float* __restrict__ Xf_n,
    unsigned short* __restrict__ Xghi_n, unsigned short* __restrict__ Xglo_n,
    const float* __restrict__ h_t, const float* __restrict__ energies,
    const float* __restrict__ enc,
    float* __restrict__ out,
    float* __restrict__ Pm, int* __restrict__ Pa,
    float* __restrict__ Pm2, int* __restrict__ Pa2,
    float* __restrict__ Ps, int t)
{
    __shared__ float Lm1[4][32], Lm2[4][32], Ls[4][32];
    __shared__ int   Li1[4][32], Li2[4][32];
    __shared__ float hrow[512], aw[128], red[256];
    int tid = threadIdx.x;
    if (blockIdx.x < 500) {
        int wave = tid >> 6, lane = tid & 63;
        int c = lane & 15, grp = lane >> 4, kg = grp * 8;
        int col = blockIdx.x * 64 + wave * 16 + c;
        const unsigned short* x0h = Xlhi_r + (size_t)c * KLIN + kg;
        const unsigned short* x0l = Xllo_r + (size_t)c * KLIN + kg;
        const unsigned short* whp = Whi + (size_t)col * KLIN + kg;
        f32x4 acc0 = {0.f,0.f,0.f,0.f}, acc1 = {0.f,0.f,0.f,0.f};
        #pragma unroll 4
        for (int k0 = 0; k0 < 1024; k0 += 32) {
            bf16x8 bh  = *(const bf16x8*)(whp + k0);
            bf16x8 a0h = *(const bf16x8*)(x0h + k0);
            bf16x8 a0l = *(const bf16x8*)(x0l + k0);
            bf16x8 a1h = *(const bf16x8*)(x0h + 16 * KLIN + k0);
            bf16x8 a1l = *(const bf16x8*)(x0l + 16 * KLIN + k0);
            acc0 = MFMA16(a0h, bh, acc0);  acc1 = MFMA16(a1h, bh, acc1);
            acc0 = MFMA16(a0l, bh, acc0);  acc1 = MFMA16(a1l, bh, acc1);
        }
        float bias = linb[col];
        float v[8];
        int r0 = grp * 4;
        #pragma unroll
        for (int i = 0; i < 4; ++i) {
            v[i]     = acc0[i] + bias;
            v[i + 4] = acc1[i] + bias;
            out[(size_t)((r0 + i) * L + t) * V + col]      = v[i];
            out[(size_t)((r0 + i + 16) * L + t) * V + col] = v[i + 4];
        }
        #pragma unroll
        for (int i = 0; i < 8; ++i) {
            float m1 = v[i]; int i1 = col; float m2 = -INFINITY; int i2 = 0x7fffffff;
            #pragma unroll
            for (int d = 1; d < 16; d <<= 1) {
                float om1 = __shfl_xor(m1, d); int oi1 = __shfl_xor(i1, d);
                float om2 = __shfl_xor(m2, d); int oi2 = __shfl_xor(i2, d);
                merge2(m1, i1, m2, i2, om1, oi1, om2, oi2);
            }
            float s = expf(v[i] - m1);
            #pragma unroll
            for (int d = 1; d < 16; d <<= 1) s += __shfl_xor(s, d);
            if (c == 0) {
                int row = (i < 4) ? r0 + i : r0 + (i - 4) + 16;
                Lm1[wave][row] = m1; Li1[wave][row] = i1;
                Lm2[wave][row] = m2; Li2[wave][row] = i2;
                Ls[wave][row] = s;
            }
        }
        __syncthreads();
        if (tid < 32) {
            float m1 = Lm1[0][tid]; int i1 = Li1[0][tid];
            float m2 = Lm2[0][tid]; int i2 = Li2[0][tid];
            #pragma unroll
            for (int q = 1; q < 4; ++q)
                merge2(m1, i1, m2, i2, Lm1[q][tid], Li1[q][tid], Lm2[q][tid], Li2[q][tid]);
            float S = 0.f;
            #pragma unroll
            for (int q = 0; q < 4; ++q) S += Ls[q][tid] * expf(Lm1[q][tid] - m1);
            Pm [tid * 500 + blockIdx.x] = m1;
            Pa [tid * 500 + blockIdx.x] = i1;
            Pm2[tid * 500 + blockIdx.x] = m2;
            Pa2[tid * 500 + blockIdx.x] = i2;
            Ps [tid * 500 + blockIdx.x] = S;
        }
    } else {
        int b = blockIdx.x - 500;
        for (int j = tid; j < 512; j += 256) hrow[j] = h_t[(size_t)j * 32 + b];
        __syncthreads();
        {
            int tt = tid >> 1, half = tid & 1;
            const float4* e4 = (const float4*)(energies + ((size_t)(b * T + tt)) * 512 + half * 256);
            const float4* h4 = (const float4*)(hrow + half * 256);
            float p = 0.f;
            #pragma unroll 4
            for (int k = 0; k < 64; ++k) {
                float4 a = e4[k], cc = h4[k];
                p += a.x * cc.x + a.y * cc.y + a.z * cc.z + a.w * cc.w;
            }
            p += __shfl_xor(p, 1);
            if (half == 0) aw[tt] = p;
        }
        __syncthreads();
        red[tid] = (tid < 128) ? aw[tid] : -INFINITY; __syncthreads();
        for (int s = 128; s > 0; s >>= 1) { if (tid < s) red[tid] = fmaxf(red[tid], red[tid + s]); __syncthreads(); }
        float am = red[0];
        __syncthreads();
        if (tid < 128) { float e = expf(aw[tid] - am); aw[tid] = e; red[tid] = e; } else red[tid] = 0.f;
        __syncthreads();
        for (int s = 128; s > 0; s >>= 1) { if (tid < s) red[tid] += red[tid + s]; __syncthreads(); }
        float asum = red[0];
        __syncthreads();
        float c0 = 0.f, c1 = 0.f;
        for (int tt2 = 0; tt2 < T; ++tt2) {
            float a = aw[tt2];
            const float* er = enc + ((size_t)(b * T + tt2)) * 512;
            c0 += a * er[tid];
            c1 += a * er[tid + 256];
        }
        c0 /= asum; c1 /= asum;
        Xf_n[(size_t)b * KLIN + 512 + tid]       = c0;
        Xf_n[(size_t)b * KLIN + 512 + tid + 256] = c1;
        split1(c0, &Xlhi_n[(size_t)b * KLIN + 512 + tid],       &Xllo_n[(size_t)b * KLIN + 512 + tid]);
        split1(c1, &Xlhi_n[(size_t)b * KLIN + 512 + tid + 256], &Xllo_n[(size_t)b * KLIN + 512 + tid + 256]);
        split1(c0, &Xghi_n[(size_t)b * KGRU + 512 + tid],       &Xglo_n[(size_t)b * KGRU + 512 + tid]);
        split1(c1, &Xghi_n[(size_t)b * KGRU + 512 + tid + 256], &Xglo_n[(size_t)b * KGRU + 512 + tid + 256]);
    }
}

// ---------- lse for t=47 ----------
__global__ void __launch_bounds__(256) lse47(
    const float* __restrict__ Pm, const float* __restrict__ Ps, float* __restrict__ lse_buf)
{
    __shared__ float sred[256];
    int b = blockIdx.x, tid = threadIdx.x;
    float m = -INFINITY;
    for (int i = tid; i < 500; i += 256) m = fmaxf(m, Pm[b * 500 + i]);
    sred[tid] = m; __syncthreads();
    for (int s = 128; s > 0; s >>= 1) { if (tid < s) sred[tid] = fmaxf(sred[tid], sred[tid + s]); __syncthreads(); }
    float M = sred[0];
    __syncthreads();
    float S = 0.f;
    for (int i = tid; i < 500; i += 256) S += Ps[b * 500 + i] * expf(Pm[b * 500 + i] - M);
    sred[tid] = S; __syncthreads();
    for (int s = 128; s > 0; s >>= 1) { if (tid < s) sred[tid] += sred[tid + s]; __syncthreads(); }
    if (tid == 0) lse_buf[b * L + 47] = M + logf(sred[0]);
}

// ---------- final: out -= lse ----------
__global__ void __launch_bounds__(256) subtract_lse(float* __restrict__ out,
                                                    const float* __restrict__ lse_buf)
{
    long i4 = (long)blockIdx.x * 256 + threadIdx.x;
    int row = (int)(i4 / 8000);
    float l = lse_buf[row];
    float4* p = (float4*)out + i4;
    float4 v = *p;
    v.x -= l; v.y -= l; v.z -= l; v.w -= l;
    *p = v;
}

extern "C" void kernel_launch(void* const* d_in, const int* in_sizes, int n_in,
                              void* d_out, int out_size, void* d_ws, size_t ws_size,
                              hipStream_t stream) {
    const int*   inputs  = (const int*)d_in[0];
    const float* context = (const float*)d_in[1];
    const float* enc     = (const float*)d_in[3];
    const float* emb     = (const float*)d_in[4];
    const float* Wih     = (const float*)d_in[5];
    const float* Whh     = (const float*)d_in[6];
    const float* bih     = (const float*)d_in[7];
    const float* bhh     = (const float*)d_in[8];
    const float* linW    = (const float*)d_in[9];
    const float* linb    = (const float*)d_in[10];
    const float* attnW   = (const float*)d_in[11];
    const float* attnb   = (const float*)d_in[12];
    float* out = (float*)d_out;

    char* w = (char*)d_ws;
    auto alloc = [&](size_t sz) { char* p = w; w += (sz + 255) & ~(size_t)255; return p; };
    unsigned short* Whi = (unsigned short*)alloc((size_t)V * KLIN * 2);      // 65.5 MB
    unsigned short* Ghi = (unsigned short*)alloc((size_t)1536 * KGRU * 2);   // 4.72 MB
    unsigned short* Glo = (unsigned short*)alloc((size_t)1536 * KGRU * 2);
    float* energies = (float*)alloc((size_t)B * T * 512 * 4);                // 8.39 MB
    float* h_t      = (float*)alloc((size_t)H * B * 4);
    unsigned short* Xghi[2]; unsigned short* Xglo[2];
    unsigned short* Xlhi[2]; unsigned short* Xllo[2];
    float* Xf[2];
    for (int q = 0; q < 2; ++q) {
        Xghi[q] = (unsigned short*)alloc((size_t)B * KGRU * 2);
        Xglo[q] = (unsigned short*)alloc((size_t)B * KGRU * 2);
        Xlhi[q] = (unsigned short*)alloc((size_t)B * KLIN * 2);
        Xllo[q] = (unsigned short*)alloc((size_t)B * KLIN * 2);
        Xf[q]   = (float*)alloc((size_t)B * KLIN * 4);
    }
    float* Pm  = (float*)alloc((size_t)B * 500 * 4);
    int*   Pa  = (int*)alloc((size_t)B * 500 * 4);
    float* Pm2 = (float*)alloc((size_t)B * 500 * 4);
    int*   Pa2 = (int*)alloc((size_t)B * 500 * 4);
    float* Ps  = (float*)alloc((size_t)B * 500 * 4);
    float* lse_buf = (float*)alloc((size_t)B * L * 4);

    presplit_lin_hi<<<16000, 256, 0, stream>>>(linW, Whi);
    presplit_gru<<<1152, 256, 0, stream>>>(Wih, Whh, Ghi, Glo);
    init_state<<<64, 256, 0, stream>>>(context, h_t,
                                       Xghi[0], Xglo[0], Xlhi[0], Xllo[0], Xf[0]);
    energies_gemm<<<dim3(128, 8), 256, 0, stream>>>(enc, attnW, attnb, energies);

    for (int t = 0; t < L; ++t) {
        int r = t & 1, n = 1 - r;
        gru_fin<<<32, 384, 0, stream>>>(
            inputs, emb, Ghi, Glo, bih, bhh, linW, linb,
            Xghi[r], Xglo[r], Xghi[n], Xglo[n],
            Xlhi[r], Xllo[r], Xf[r], Xf[n],
            h_t, Pm, Pa, Pm2, Pa2, Ps, lse_buf, t);
        score_attn<<<532, 256, 0, stream>>>(
            Whi, linb, Xlhi[r], Xllo[r],
            Xlhi[n], Xllo[n], Xf[n],
            Xghi[n], Xglo[n],
            h_t, energies, enc, out,
            Pm, Pa, Pm2, Pa2, Ps, t);
    }
    lse47<<<32, 256, 0, stream>>>(Pm, Ps, lse_buf);
    subtract_lse<<<48000, 256, 0, stream>>>(out, lse_buf);
}

// Round 10
// 5303.794 us; speedup vs baseline: 1.5963x; 1.5963x over previous
//
#include <hip/hip_runtime.h>
#include <hip/hip_bf16.h>

#define V  32000
#define D  512
#define H  512
#define B  32
#define T  128
#define L  48
#define KLIN 1024
#define KGRU 1536
#define RESCUE_DELTA 0.04f
#define MAXCAND 64

typedef __attribute__((ext_vector_type(8))) short bf16x8;
typedef __attribute__((ext_vector_type(4))) float f32x4;

#define MFMA16(a, b, c) __builtin_amdgcn_mfma_f32_16x16x32_bf16(a, b, c, 0, 0, 0)

// ---------- f32 -> (bf16 hi, bf16 lo) split, RNE ----------
__device__ __forceinline__ void split1(float f, unsigned short* hi, unsigned short* lo) {
    unsigned u  = __float_as_uint(f);
    unsigned uh = u + (0x7FFFu + ((u >> 16) & 1u));
    unsigned short hs = (unsigned short)(uh >> 16);
    float hf = __uint_as_float(((unsigned)hs) << 16);
    float l  = f - hf;
    unsigned ul = __float_as_uint(l);
    ul += 0x7FFFu + ((ul >> 16) & 1u);
    *hi = hs;
    *lo = (unsigned short)(ul >> 16);
}

__device__ __forceinline__ void split8(const float* __restrict__ p, bf16x8& hi, bf16x8& lo) {
    float4 w0 = reinterpret_cast<const float4*>(p)[0];
    float4 w1 = reinterpret_cast<const float4*>(p)[1];
    float w[8] = {w0.x, w0.y, w0.z, w0.w, w1.x, w1.y, w1.z, w1.w};
    #pragma unroll
    for (int i = 0; i < 8; ++i) {
        unsigned u  = __float_as_uint(w[i]);
        unsigned uh = u + (0x7FFFu + ((u >> 16) & 1u));
        unsigned short hs = (unsigned short)(uh >> 16);
        float hf = __uint_as_float(((unsigned)hs) << 16);
        float l  = w[i] - hf;
        unsigned ul = __float_as_uint(l);
        ul += 0x7FFFu + ((ul >> 16) & 1u);
        hi[i] = (short)hs;
        lo[i] = (short)(ul >> 16);
    }
}

// top-2 merge
__device__ __forceinline__ void merge2(float& m1, int& i1, float& m2, int& i2,
                                       float om1, int oi1, float om2, int oi2) {
    bool ogt = (om1 > m1) || (om1 == m1 && oi1 < i1);
    float t1 = ogt ? om1 : m1; int ti1 = ogt ? oi1 : i1;
    float l1 = ogt ? m1 : om1; int li1 = ogt ? i1 : oi1;
    float w2 = ogt ? om2 : m2; int wi2 = ogt ? oi2 : i2;
    bool lgt = (l1 > w2) || (l1 == w2 && li1 < wi2);
    m1 = t1; i1 = ti1;
    m2 = lgt ? l1 : w2; i2 = lgt ? li1 : wi2;
}

// packed sortable (value, col) for u64 atomicMax; tie -> lowest col wins
__device__ __forceinline__ unsigned long long packmax(float v, int col) {
    unsigned u = __float_as_uint(v);
    u = (u & 0x80000000u) ? ~u : (u | 0x80000000u);
    return ((unsigned long long)u << 32) | (unsigned)(0x7fffffff - col);
}
__device__ __forceinline__ float unpack_val(unsigned long long p) {
    unsigned u = (unsigned)(p >> 32);
    u = (u & 0x80000000u) ? (u & 0x7fffffffu) : ~u;
    return __uint_as_float(u);
}
__device__ __forceinline__ int unpack_col(unsigned long long p) {
    return 0x7fffffff - (int)(unsigned)(p & 0xffffffffu);
}

// ---------- one-time: linW -> bf16 hi only ----------
__global__ void presplit_lin_hi(const float* __restrict__ src, unsigned short* __restrict__ hi)
{
    long i = (long)blockIdx.x * 256 + threadIdx.x;
    if (i >= (long)V * 128) return;
    bf16x8 h8, l8;
    split8(src + i * 8, h8, l8);
    *(bf16x8*)(hi + i * 8) = h8;
}

// ---------- one-time: split gru weights into combined [1536][1536] K-layout ----------
__global__ void presplit_gru(const float* __restrict__ Wih, const float* __restrict__ Whh,
                             unsigned short* __restrict__ hi, unsigned short* __restrict__ lo)
{
    int i = blockIdx.x * 256 + threadIdx.x;
    if (i >= 1536 * 192) return;
    int col = i / 192, k = (i % 192) * 8;
    const float* src = (k < 1024) ? (Wih + (size_t)col * 1024 + k)
                                  : (Whh + (size_t)col * 512 + (k - 1024));
    bf16x8 h8, l8;
    split8(src, h8, l8);
    *(bf16x8*)(hi + (size_t)col * KGRU + k) = h8;
    *(bf16x8*)(lo + (size_t)col * KGRU + k) = l8;
}

// ---------- init ----------
__global__ void init_state(const float* __restrict__ context, float* __restrict__ h_t,
                           unsigned short* __restrict__ Xghi, unsigned short* __restrict__ Xglo,
                           unsigned short* __restrict__ Xlhi, unsigned short* __restrict__ Xllo,
                           float* __restrict__ Xf)
{
    int idx = blockIdx.x * 256 + threadIdx.x;   // 0..B*H-1
    int b = idx >> 9, j = idx & 511;
    float c = context[b * H + j];
    split1(c, &Xghi[b * KGRU + 512 + j], &Xglo[b * KGRU + 512 + j]);
    split1(c, &Xlhi[b * KLIN + 512 + j], &Xllo[b * KLIN + 512 + j]);
    Xf[b * KLIN + 512 + j] = c;
    Xghi[b * KGRU + 1024 + j] = 0;
    Xglo[b * KGRU + 1024 + j] = 0;
    h_t[j * 32 + b] = 0.f;
}

// ---------- energies = enc @ attn_W^T + attn_b (once) ----------
__global__ void __launch_bounds__(256) energies_gemm(
    const float* __restrict__ enc, const float* __restrict__ attnW,
    const float* __restrict__ attnb, float* __restrict__ energies)
{
    int wave = threadIdx.x >> 6, lane = threadIdx.x & 63;
    int col = blockIdx.y * 64 + wave * 16 + (lane & 15);
    int kg  = (lane >> 4) * 8;
    int arow0 = blockIdx.x * 32 + (lane & 15);
    f32x4 acc0 = {0.f,0.f,0.f,0.f}, acc1 = {0.f,0.f,0.f,0.f};
    for (int k0 = 0; k0 < 512; k0 += 32) {
        bf16x8 bh, bl;   split8(attnW + (size_t)col * 512 + k0 + kg, bh, bl);
        bf16x8 a0h, a0l; split8(enc + (size_t)arow0 * 512 + k0 + kg, a0h, a0l);
        bf16x8 a1h, a1l; split8(enc + (size_t)(arow0 + 16) * 512 + k0 + kg, a1h, a1l);
        acc0 = MFMA16(a0h, bh, acc0);  acc1 = MFMA16(a1h, bh, acc1);
        acc0 = MFMA16(a0l, bh, acc0);  acc1 = MFMA16(a1l, bh, acc1);
        acc0 = MFMA16(a0h, bl, acc0);  acc1 = MFMA16(a1h, bl, acc1);
    }
    float bias = attnb[col];
    int r0 = (lane >> 4) * 4;
    #pragma unroll
    for (int i = 0; i < 4; ++i) {
        int row = blockIdx.x * 32 + r0 + i;
        energies[(size_t)row * 512 + col]        = acc0[i] + bias;
        energies[(size_t)(row + 16) * 512 + col] = acc1[i] + bias;
    }
}

// ---------- GRU(t): 32 blocks x 384; argmax(t-1) read from amax_ex (32 u64 loads) ----------
__global__ void __launch_bounds__(384) gru_fin(
    const int* __restrict__ inputs, const float* __restrict__ emb,
    const unsigned short* __restrict__ Ghi, const unsigned short* __restrict__ Glo,
    const float* __restrict__ bih, const float* __restrict__ bhh,
    const unsigned short* __restrict__ Xghi_r, const unsigned short* __restrict__ Xglo_r,
    unsigned short* __restrict__ Xghi_n, unsigned short* __restrict__ Xglo_n,
    unsigned short* __restrict__ Xlhi_w, unsigned short* __restrict__ Xllo_w,
    float* __restrict__ Xf_w, float* __restrict__ h_t,
    const unsigned long long* __restrict__ amax_prev, int t)
{
    __shared__ float AI[3][32][16], AH[3][32][16];
    __shared__ float R[32][16], Z[32][16];
    __shared__ int   sAl[32];
    const int tid = threadIdx.x;
    const int w = tid >> 6, lane = tid & 63;

    if (tid < 32) {
        int col;
        if (t == 0) col = inputs[tid];
        else {
            col = unpack_col(amax_prev[tid]);
            if (col < 0 || col >= V) col = 0;   // insurance: never OOB
        }
        sAl[tid] = col;
    }
    __syncthreads();

    {
        int g = (w < 3) ? w : w - 3;
        int c = lane & 15, grp = lane >> 4, kg = grp * 8;
        int j = blockIdx.x * 16 + c;
        int gcol = g * 512 + j;
        const unsigned short* wh = Ghi + (size_t)gcol * KGRU;
        const unsigned short* wl = Glo + (size_t)gcol * KGRU;
        const unsigned short* xh = Xghi_r + (size_t)c * KGRU;
        const unsigned short* xl = Xglo_r + (size_t)c * KGRU;
        f32x4 aI0 = {0.f,0.f,0.f,0.f}, aI1 = {0.f,0.f,0.f,0.f};
        f32x4 aH0 = {0.f,0.f,0.f,0.f}, aH1 = {0.f,0.f,0.f,0.f};
        if (w < 3) {
            const float* e0p = emb + (size_t)sAl[c] * 512;
            const float* e1p = emb + (size_t)sAl[c + 16] * 512;
            for (int k0 = 0; k0 < 512; k0 += 32) {
                bf16x8 bh = *(const bf16x8*)(wh + k0 + kg);
                bf16x8 bl = *(const bf16x8*)(wl + k0 + kg);
                bf16x8 a0h, a0l, a1h, a1l;
                split8(e0p + k0 + kg, a0h, a0l);
                split8(e1p + k0 + kg, a1h, a1l);
                aI0 = MFMA16(a0h, bh, aI0);  aI1 = MFMA16(a1h, bh, aI1);
                aI0 = MFMA16(a0l, bh, aI0);  aI1 = MFMA16(a1l, bh, aI1);
                aI0 = MFMA16(a0h, bl, aI0);  aI1 = MFMA16(a1h, bl, aI1);
            }
            for (int k0 = 1024; k0 < 1280; k0 += 32) {
                bf16x8 bh = *(const bf16x8*)(wh + k0 + kg);
                bf16x8 bl = *(const bf16x8*)(wl + k0 + kg);
                bf16x8 a0h = *(const bf16x8*)(xh + k0 + kg);
                bf16x8 a0l = *(const bf16x8*)(xl + k0 + kg);
                bf16x8 a1h = *(const bf16x8*)(xh + 16 * KGRU + k0 + kg);
                bf16x8 a1l = *(const bf16x8*)(xl + 16 * KGRU + k0 + kg);
                aH0 = MFMA16(a0h, bh, aH0);  aH1 = MFMA16(a1h, bh, aH1);
                aH0 = MFMA16(a0l, bh, aH0);  aH1 = MFMA16(a1l, bh, aH1);
                aH0 = MFMA16(a0h, bl, aH0);  aH1 = MFMA16(a1h, bl, aH1);
            }
        } else {
            for (int k0 = 512; k0 < 1024; k0 += 32) {
                bf16x8 bh = *(const bf16x8*)(wh + k0 + kg);
                bf16x8 bl = *(const bf16x8*)(wl + k0 + kg);
                bf16x8 a0h = *(const bf16x8*)(xh + k0 + kg);
                bf16x8 a0l = *(const bf16x8*)(xl + k0 + kg);
                bf16x8 a1h = *(const bf16x8*)(xh + 16 * KGRU + k0 + kg);
                bf16x8 a1l = *(const bf16x8*)(xl + 16 * KGRU + k0 + kg);
                aI0 = MFMA16(a0h, bh, aI0);  aI1 = MFMA16(a1h, bh, aI1);
                aI0 = MFMA16(a0l, bh, aI0);  aI1 = MFMA16(a1l, bh, aI1);
                aI0 = MFMA16(a0h, bl, aI0);  aI1 = MFMA16(a1h, bl, aI1);
            }
            for (int k0 = 1280; k0 < 1536; k0 += 32) {
                bf16x8 bh = *(const bf16x8*)(wh + k0 + kg);
                bf16x8 bl = *(const bf16x8*)(wl + k0 + kg);
                bf16x8 a0h = *(const bf16x8*)(xh + k0 + kg);
                bf16x8 a0l = *(const bf16x8*)(xl + k0 + kg);
                bf16x8 a1h = *(const bf16x8*)(xh + 16 * KGRU + k0 + kg);
                bf16x8 a1l = *(const bf16x8*)(xl + 16 * KGRU + k0 + kg);
                aH0 = MFMA16(a0h, bh, aH0);  aH1 = MFMA16(a1h, bh, aH1);
                aH0 = MFMA16(a0l, bh, aH0);  aH1 = MFMA16(a1l, bh, aH1);
                aH0 = MFMA16(a0h, bl, aH0);  aH1 = MFMA16(a1h, bl, aH1);
            }
        }
        if (w >= 3) {
            #pragma unroll
            for (int i = 0; i < 4; ++i) {
                AI[g][grp * 4 + i][c] = aI0[i];  AI[g][grp * 4 + i + 16][c] = aI1[i];
                AH[g][grp * 4 + i][c] = aH0[i];  AH[g][grp * 4 + i + 16][c] = aH1[i];
            }
        }
        __syncthreads();
        float gi[8], gh[8];
        if (w < 3) {
            float bi = bih[gcol], bhv = bhh[gcol];
            #pragma unroll
            for (int i = 0; i < 4; ++i) {
                gi[i]     = aI0[i] + AI[g][grp * 4 + i][c]      + bi;
                gi[i + 4] = aI1[i] + AI[g][grp * 4 + i + 16][c] + bi;
                gh[i]     = aH0[i] + AH[g][grp * 4 + i][c]      + bhv;
                gh[i + 4] = aH1[i] + AH[g][grp * 4 + i + 16][c] + bhv;
            }
            if (w == 0) {
                #pragma unroll
                for (int i = 0; i < 8; ++i) {
                    int b = (i < 4) ? grp * 4 + i : grp * 4 + (i - 4) + 16;
                    R[b][c] = 1.f / (1.f + expf(-(gi[i] + gh[i])));
                }
            } else if (w == 1) {
                #pragma unroll
                for (int i = 0; i < 8; ++i) {
                    int b = (i < 4) ? grp * 4 + i : grp * 4 + (i - 4) + 16;
                    Z[b][c] = 1.f / (1.f + expf(-(gi[i] + gh[i])));
                }
            }
        }
        __syncthreads();
        if (w == 2) {
            float4 h0 = *(const float4*)(h_t + (size_t)j * 32 + grp * 4);
            float4 h1 = *(const float4*)(h_t + (size_t)j * 32 + grp * 4 + 16);
            float hold[8] = {h0.x, h0.y, h0.z, h0.w, h1.x, h1.y, h1.z, h1.w};
            float hn[8];
            #pragma unroll
            for (int i = 0; i < 8; ++i) {
                int b = (i < 4) ? grp * 4 + i : grp * 4 + (i - 4) + 16;
                float n = tanhf(gi[i] + R[b][c] * gh[i]);
                float z = Z[b][c];
                hn[i] = (1.f - z) * n + z * hold[i];
            }
            *(float4*)(h_t + (size_t)j * 32 + grp * 4)      = make_float4(hn[0], hn[1], hn[2], hn[3]);
            *(float4*)(h_t + (size_t)j * 32 + grp * 4 + 16) = make_float4(hn[4], hn[5], hn[6], hn[7]);
            #pragma unroll
            for (int i = 0; i < 8; ++i) {
                int b = (i < 4) ? grp * 4 + i : grp * 4 + (i - 4) + 16;
                split1(hn[i], &Xlhi_w[(size_t)b * KLIN + j], &Xllo_w[(size_t)b * KLIN + j]);
                Xf_w[(size_t)b * KLIN + j] = hn[i];
                split1(hn[i], &Xghi_n[(size_t)b * KGRU + 1024 + j], &Xglo_n[(size_t)b * KGRU + 1024 + j]);
            }
        }
    }
}

// ---------- score (2-pass Whi; blocks 0..499) + attention (500..531) ----------
__global__ void __launch_bounds__(256) score_attn(
    const unsigned short* __restrict__ Whi, const float* __restrict__ linb,
    const float* __restrict__ linW,
    const unsigned short* __restrict__ Xlhi_r, const unsigned short* __restrict__ Xllo_r,
    const float* __restrict__ Xf_c,
    unsigned short* __restrict__ Xlhi_n, unsigned short* __restrict__ Xllo_n,
    float* __restrict__ Xf_n,
    unsigned short* __restrict__ Xghi_n, unsigned short* __restrict__ Xglo_n,
    const float* __restrict__ h_t, const float* __restrict__ energies,
    const float* __restrict__ enc,
    float* __restrict__ out,
    float* __restrict__ PmT, float* __restrict__ PsT,
    unsigned long long* __restrict__ amax_ap, unsigned long long* __restrict__ amax_ex,
    int t)
{
    __shared__ float Lm1[4][32], Lm2[4][32], Ls[4][32];
    __shared__ int   Li1[4][32], Li2[4][32];
    __shared__ float hrow[512], aw[128], red[256];
    __shared__ int   glist_b[MAXCAND], glist_c[MAXCAND];
    __shared__ int   gcount;
    int tid = threadIdx.x;
    if (blockIdx.x < 500) {
        int wave = tid >> 6, lane = tid & 63;
        int c = lane & 15, grp = lane >> 4, kg = grp * 8;
        int col = blockIdx.x * 64 + wave * 16 + c;
        const unsigned short* x0h = Xlhi_r + (size_t)c * KLIN + kg;
        const unsigned short* x0l = Xllo_r + (size_t)c * KLIN + kg;
        const unsigned short* whp = Whi + (size_t)col * KLIN + kg;
        f32x4 acc0 = {0.f,0.f,0.f,0.f}, acc1 = {0.f,0.f,0.f,0.f};
        #pragma unroll 4
        for (int k0 = 0; k0 < 1024; k0 += 32) {
            bf16x8 bh  = *(const bf16x8*)(whp + k0);
            bf16x8 a0h = *(const bf16x8*)(x0h + k0);
            bf16x8 a0l = *(const bf16x8*)(x0l + k0);
            bf16x8 a1h = *(const bf16x8*)(x0h + 16 * KLIN + k0);
            bf16x8 a1l = *(const bf16x8*)(x0l + 16 * KLIN + k0);
            acc0 = MFMA16(a0h, bh, acc0);  acc1 = MFMA16(a1h, bh, acc1);
            acc0 = MFMA16(a0l, bh, acc0);  acc1 = MFMA16(a1l, bh, acc1);
        }
        float bias = linb[col];
        float v[8];
        int r0 = grp * 4;
        #pragma unroll
        for (int i = 0; i < 4; ++i) {
            v[i]     = acc0[i] + bias;
            v[i + 4] = acc1[i] + bias;
            out[(size_t)((r0 + i) * L + t) * V + col]      = v[i];
            out[(size_t)((r0 + i + 16) * L + t) * V + col] = v[i + 4];
        }
        #pragma unroll
        for (int i = 0; i < 8; ++i) {
            float m1 = v[i]; int i1 = col; float m2 = -INFINITY; int i2 = 0x7fffffff;
            #pragma unroll
            for (int d = 1; d < 16; d <<= 1) {
                float om1 = __shfl_xor(m1, d); int oi1 = __shfl_xor(i1, d);
                float om2 = __shfl_xor(m2, d); int oi2 = __shfl_xor(i2, d);
                merge2(m1, i1, m2, i2, om1, oi1, om2, oi2);
            }
            float s = expf(v[i] - m1);
            #pragma unroll
            for (int d = 1; d < 16; d <<= 1) s += __shfl_xor(s, d);
            if (c == 0) {
                int row = (i < 4) ? r0 + i : r0 + (i - 4) + 16;
                Lm1[wave][row] = m1; Li1[wave][row] = i1;
                Lm2[wave][row] = m2; Li2[wave][row] = i2;
                Ls[wave][row] = s;
            }
        }
        if (tid == 0) gcount = 0;
        __syncthreads();
        if (tid < 32) {
            float m1 = Lm1[0][tid]; int i1 = Li1[0][tid];
            float m2 = Lm2[0][tid]; int i2 = Li2[0][tid];
            #pragma unroll
            for (int q = 1; q < 4; ++q)
                merge2(m1, i1, m2, i2, Lm1[q][tid], Li1[q][tid], Lm2[q][tid], Li2[q][tid]);
            float S = 0.f;
            #pragma unroll
            for (int q = 0; q < 4; ++q) S += Ls[q][tid] * expf(Lm1[q][tid] - m1);
            PmT[tid * 500 + blockIdx.x] = m1;
            PsT[tid * 500 + blockIdx.x] = S;
            // post our approx max, then gate against the freshest visible global max
            unsigned long long mypack = packmax(m1, i1);
            unsigned long long old = atomicMax(&amax_ap[tid], mypack);
            unsigned long long cur = old > mypack ? old : mypack;
            unsigned long long fresh = __hip_atomic_load(&amax_ap[tid], __ATOMIC_RELAXED,
                                                         __HIP_MEMORY_SCOPE_AGENT);
            if (fresh > cur) cur = fresh;
            float stale = unpack_val(cur);
            if (m1 >= stale - RESCUE_DELTA) {
                int p = atomicAdd(&gcount, 1);
                if (p < MAXCAND) { glist_b[p] = tid; glist_c[p] = i1; }
            }
            if (m2 >= stale - RESCUE_DELTA) {
                int p = atomicAdd(&gcount, 1);
                if (p < MAXCAND) { glist_b[p] = tid; glist_c[p] = i2; }
            }
        }
        __syncthreads();
        int ng = gcount < MAXCAND ? gcount : MAXCAND;
        for (int ci = wave; ci < ng; ci += 4) {
            int b = glist_b[ci], colc = glist_c[ci];
            const float* wr = linW + (size_t)colc * 1024 + lane * 16;
            const float* xr = Xf_c + (size_t)b * KLIN + lane * 16;
            float s = 0.f;
            #pragma unroll
            for (int jj = 0; jj < 16; jj += 4) {
                float4 av = *(const float4*)(wr + jj);
                float4 xv = *(const float4*)(xr + jj);
                s += av.x * xv.x + av.y * xv.y + av.z * xv.z + av.w * xv.w;
            }
            #pragma unroll
            for (int d = 1; d < 64; d <<= 1) s += __shfl_xor(s, d);
            if (lane == 0) atomicMax(&amax_ex[b], packmax(s + linb[colc], colc));
        }
    } else {
        int b = blockIdx.x - 500;
        for (int j = tid; j < 512; j += 256) hrow[j] = h_t[(size_t)j * 32 + b];
        __syncthreads();
        {
            int tt = tid >> 1, half = tid & 1;
            const float4* e4 = (const float4*)(energies + ((size_t)(b * T + tt)) * 512 + half * 256);
            const float4* h4 = (const float4*)(hrow + half * 256);
            float p = 0.f;
            #pragma unroll 4
            for (int k = 0; k < 64; ++k) {
                float4 a = e4[k], cc = h4[k];
                p += a.x * cc.x + a.y * cc.y + a.z * cc.z + a.w * cc.w;
            }
            p += __shfl_xor(p, 1);
            if (half == 0) aw[tt] = p;
        }
        __syncthreads();
        red[tid] = (tid < 128) ? aw[tid] : -INFINITY; __syncthreads();
        for (int s = 128; s > 0; s >>= 1) { if (tid < s) red[tid] = fmaxf(red[tid], red[tid + s]); __syncthreads(); }
        float am = red[0];
        __syncthreads();
        if (tid < 128) { float e = expf(aw[tid] - am); aw[tid] = e; red[tid] = e; } else red[tid] = 0.f;
        __syncthreads();
        for (int s = 128; s > 0; s >>= 1) { if (tid < s) red[tid] += red[tid + s]; __syncthreads(); }
        float asum = red[0];
        __syncthreads();
        float c0 = 0.f, c1 = 0.f;
        for (int tt2 = 0; tt2 < T; ++tt2) {
            float a = aw[tt2];
            const float* er = enc + ((size_t)(b * T + tt2)) * 512;
            c0 += a * er[tid];
            c1 += a * er[tid + 256];
        }
        c0 /= asum; c1 /= asum;
        Xf_n[(size_t)b * KLIN + 512 + tid]       = c0;
        Xf_n[(size_t)b * KLIN + 512 + tid + 256] = c1;
        split1(c0, &Xlhi_n[(size_t)b * KLIN + 512 + tid],       &Xllo_n[(size_t)b * KLIN + 512 + tid]);
        split1(c1, &Xlhi_n[(size_t)b * KLIN + 512 + tid + 256], &Xllo_n[(size_t)b * KLIN + 512 + tid + 256]);
        split1(c0, &Xghi_n[(size_t)b * KGRU + 512 + tid],       &Xglo_n[(size_t)b * KGRU + 512 + tid]);
        split1(c1, &Xghi_n[(size_t)b * KGRU + 512 + tid + 256], &Xglo_n[(size_t)b * KGRU + 512 + tid + 256]);
    }
}

// ---------- epilogue: lse for all (t,b) from stored partials ----------
__global__ void __launch_bounds__(256) lse_all(
    const float* __restrict__ PmAll, const float* __restrict__ PsAll,
    float* __restrict__ lse_buf)
{
    __shared__ float sred[256];
    int t = blockIdx.x >> 5, b = blockIdx.x & 31, tid = threadIdx.x;
    const float* Pm = PmAll + ((size_t)t * 32 + b) * 500;
    const float* Ps = PsAll + ((size_t)t * 32 + b) * 500;
    float m = -INFINITY;
    for (int i = tid; i < 500; i += 256) m = fmaxf(m, Pm[i]);
    sred[tid] = m; __syncthreads();
    for (int s = 128; s > 0; s >>= 1) { if (tid < s) sred[tid] = fmaxf(sred[tid], sred[tid + s]); __syncthreads(); }
    float M = sred[0];
    __syncthreads();
    float S = 0.f;
    for (int i = tid; i < 500; i += 256) S += Ps[i] * expf(Pm[i] - M);
    sred[tid] = S; __syncthreads();
    for (int s = 128; s > 0; s >>= 1) { if (tid < s) sred[tid] += sred[tid + s]; __syncthreads(); }
    if (tid == 0) lse_buf[b * L + t] = M + logf(sred[0]);
}

// ---------- final: out -= lse ----------
__global__ void __launch_bounds__(256) subtract_lse(float* __restrict__ out,
                                                    const float* __restrict__ lse_buf)
{
    long i4 = (long)blockIdx.x * 256 + threadIdx.x;
    int row = (int)(i4 / 8000);
    float l = lse_buf[row];
    float4* p = (float4*)out + i4;
    float4 v = *p;
    v.x -= l; v.y -= l; v.z -= l; v.w -= l;
    *p = v;
}

extern "C" void kernel_launch(void* const* d_in, const int* in_sizes, int n_in,
                              void* d_out, int out_size, void* d_ws, size_t ws_size,
                              hipStream_t stream) {
    const int*   inputs  = (const int*)d_in[0];
    const float* context = (const float*)d_in[1];
    const float* enc     = (const float*)d_in[3];
    const float* emb     = (const float*)d_in[4];
    const float* Wih     = (const float*)d_in[5];
    const float* Whh     = (const float*)d_in[6];
    const float* bih     = (const float*)d_in[7];
    const float* bhh     = (const float*)d_in[8];
    const float* linW    = (const float*)d_in[9];
    const float* linb    = (const float*)d_in[10];
    const float* attnW   = (const float*)d_in[11];
    const float* attnb   = (const float*)d_in[12];
    float* out = (float*)d_out;

    char* w = (char*)d_ws;
    auto alloc = [&](size_t sz) { char* p = w; w += (sz + 255) & ~(size_t)255; return p; };
    unsigned short* Whi = (unsigned short*)alloc((size_t)V * KLIN * 2);      // 65.5 MB
    unsigned short* Ghi = (unsigned short*)alloc((size_t)1536 * KGRU * 2);   // 4.72 MB
    unsigned short* Glo = (unsigned short*)alloc((size_t)1536 * KGRU * 2);
    float* energies = (float*)alloc((size_t)B * T * 512 * 4);                // 8.39 MB
    float* h_t      = (float*)alloc((size_t)H * B * 4);
    unsigned short* Xghi[2]; unsigned short* Xglo[2];
    unsigned short* Xlhi[2]; unsigned short* Xllo[2];
    float* Xf[2];
    for (int q = 0; q < 2; ++q) {
        Xghi[q] = (unsigned short*)alloc((size_t)B * KGRU * 2);
        Xglo[q] = (unsigned short*)alloc((size_t)B * KGRU * 2);
        Xlhi[q] = (unsigned short*)alloc((size_t)B * KLIN * 2);
        Xllo[q] = (unsigned short*)alloc((size_t)B * KLIN * 2);
        Xf[q]   = (float*)alloc((size_t)B * KLIN * 4);
    }
    float* PmAll = (float*)alloc((size_t)L * 32 * 500 * 4);                  // 3.07 MB
    float* PsAll = (float*)alloc((size_t)L * 32 * 500 * 4);
    float* lse_buf = (float*)alloc((size_t)B * L * 4);
    unsigned long long* amax_ap = (unsigned long long*)alloc((size_t)L * 32 * 8);
    unsigned long long* amax_ex = (unsigned long long*)alloc((size_t)L * 32 * 8);

    hipMemsetAsync(amax_ap, 0, (size_t)L * 32 * 8, stream);
    hipMemsetAsync(amax_ex, 0, (size_t)L * 32 * 8, stream);
    presplit_lin_hi<<<16000, 256, 0, stream>>>(linW, Whi);
    presplit_gru<<<1152, 256, 0, stream>>>(Wih, Whh, Ghi, Glo);
    init_state<<<64, 256, 0, stream>>>(context, h_t,
                                       Xghi[0], Xglo[0], Xlhi[0], Xllo[0], Xf[0]);
    energies_gemm<<<dim3(128, 8), 256, 0, stream>>>(enc, attnW, attnb, energies);

    for (int t = 0; t < L; ++t) {
        int r = t & 1, n = 1 - r;
        gru_fin<<<32, 384, 0, stream>>>(
            inputs, emb, Ghi, Glo, bih, bhh,
            Xghi[r], Xglo[r], Xghi[n], Xglo[n],
            Xlhi[r], Xllo[r], Xf[r], h_t,
            amax_ex + (size_t)(t - 1) * 32, t);
        score_attn<<<532, 256, 0, stream>>>(
            Whi, linb, linW,
            Xlhi[r], Xllo[r], Xf[r],
            Xlhi[n], Xllo[n], Xf[n],
            Xghi[n], Xglo[n],
            h_t, energies, enc, out,
            PmAll + (size_t)t * 32 * 500, PsAll + (size_t)t * 32 * 500,
            amax_ap + (size_t)t * 32, amax_ex + (size_t)t * 32, t);
    }
    lse_all<<<L * 32, 256, 0, stream>>>(PmAll, PsAll, lse_buf);
    subtract_lse<<<48000, 256, 0, stream>>>(out, lse_buf);
}